// Round 10
// baseline (967.557 us; speedup 1.0000x reference)
//
#include <hip/hip_runtime.h>
#include <math.h>

namespace {

constexpr int B = 8, T = 10, C = 32, H = 128, W = 128;
constexpr int HW = H * W;            // 16384
constexpr int CHW = C * HW;          // 524288
constexpr int BHW = B * HW;
constexpr long long NSTATE = (long long)B * CHW;

constexpr float DF = 0.90483741803595952f;  // exp(-0.1)
constexpr float DL = 0.36787944117144233f;  // exp(-1.0)
constexpr float DE = 0.36787944117144233f;  // exp(-1.0)
constexpr float VE = 10.0f;
constexpr float E0 = 3.6787944117144233f;   // DE * (V_E/ALPHA_E), e-fold init

// wgt[co][ci][kh][kw] -> wtr[ci][k][co]   (9216 floats)
__global__ void k_wtr(const float* __restrict__ wgt, float* __restrict__ wtr) {
  int i = blockIdx.x * 256 + threadIdx.x;
  if (i >= C * C * 9) return;
  int ci = i / 288;
  int k = (i / 32) % 9;
  int co = i & 31;
  wtr[i] = wgt[co * 288 + ci * 9 + k];
}

// t=0: y_prev=0 -> conv=0, l=0, u=f. Writes f, e_used(1), out[0], s(2-plane), l.
__launch_bounds__(256, 2)
__global__ void k_step0(const float* __restrict__ x, const float* __restrict__ bias,
                        float* __restrict__ f, float* __restrict__ e,
                        float* __restrict__ lpl, float* __restrict__ out,
                        float* __restrict__ s_out) {
  __shared__ float sred[8][32][4];
  const int tid = threadIdx.x, bid = blockIdx.x;
  const int tw = bid & 7, th = (bid >> 3) & 15, b = bid >> 7;
  const int h0 = th * 8, w0 = tw * 16;
  const int g = tid >> 5, s = tid & 31;
  const int sh = s >> 2, sw = s & 3, cb = 4 * sw;
  const int gh = h0 + sh, gwc = w0 + cb;
  const float4 bc4 = *(const float4*)&bias[4 * g];
  const float bc[4] = {bc4.x, bc4.y, bc4.z, bc4.w};

  float sp[4] = {0.f, 0.f, 0.f, 0.f};
#pragma unroll
  for (int q = 0; q < 4; ++q) {
    const int c = 4 * g + q;
    const size_t sidx = (size_t)b * CHW + (size_t)c * HW + (size_t)gh * W + gwc;
    const size_t oidx = (((size_t)b * T) * C + c) * (size_t)HW + (size_t)gh * W + gwc;
    float4 x4 = *(const float4*)(x + oidx);
    float xr[4] = {x4.x, x4.y, x4.z, x4.w};
    float fo[4], eo[4], yn[4];
#pragma unroll
    for (int p = 0; p < 4; ++p) {
      float fn = bc[q] + xr[p];                  // DF*0 + conv(0) + bias + x
      float yy = 1.f / (1.f + __expf(E0 - fn));  // u = fn (l=0)
      fo[p] = fn;
      eo[p] = DE * E0 + VE * yy;                 // e_used(1)
      yn[p] = yy;
      sp[p] += yy;
    }
    *(float4*)(f + sidx) = make_float4(fo[0], fo[1], fo[2], fo[3]);
    *(float4*)(e + sidx) = make_float4(eo[0], eo[1], eo[2], eo[3]);
    *(float4*)(out + oidx) = make_float4(yn[0], yn[1], yn[2], yn[3]);
  }
  *(float4*)&sred[g][s][0] = make_float4(sp[0], sp[1], sp[2], sp[3]);
  __syncthreads();
  if (tid < 32) {
    float4 a = *(const float4*)&sred[0][tid][0];
#pragma unroll
    for (int gg = 1; gg < 8; ++gg) {
      float4 bq = *(const float4*)&sred[gg][tid][0];
      a.x += bq.x; a.y += bq.y; a.z += bq.z; a.w += bq.w;
    }
    const size_t pidx = (size_t)b * HW + (size_t)gh * W + gwc;
    *(float4*)(s_out + pidx) = a;                                   // plane 0
    *(float4*)(s_out + BHW + pidx) = make_float4(0.f, 0.f, 0.f, 0.f);  // plane 1
    *(float4*)(lpl + pidx) = make_float4(0.f, 0.f, 0.f, 0.f);       // l_1 = 0
  }
}

// Steps 1..T-1. 2048 blocks x 256 threads: tile 8 rows x 16 cols, 16 c_out
// per block (co-split across 2 blocks -> 2x blocks vs R9 for latency hiding).
// Thread: g=tid>>5 owns c_out {base+2g, base+2g+1}; s=tid&31 -> 4-px strip.
// ci in 4 chunks of 8, single LDS buffer + register prefetch (T14).
// Chansum: each co-half writes its partial plane; next step sums both planes.
__launch_bounds__(256, 2)
__global__ void k_step(const float* __restrict__ x, const float* __restrict__ wtr,
                       const float* __restrict__ bias, const float* __restrict__ s_in,
                       float* __restrict__ s_out, float* __restrict__ f,
                       float* __restrict__ e, float* __restrict__ lpl,
                       float* __restrict__ out, int t) {
  __shared__ float ysl[8][10][28];   // stride 28: rows 16B-aligned, 2-way banks
  __shared__ float wsl[8][9][16];    // [ci][k][c_out-half]
  __shared__ float sl[10][21];       // channel-sum tile (+halo)
  __shared__ float sred[8][32][4];   // chansum partials (this half)

  const int tid = threadIdx.x, bid = blockIdx.x;
  const int half = bid & 1;
  const int tw = (bid >> 1) & 7, th = (bid >> 4) & 15, b = bid >> 8;
  const int h0 = th * 8, w0 = tw * 16;
  const int g = tid >> 5, s = tid & 31;
  const int sh = s >> 2, sw = s & 3, cb = 4 * sw;
  const int gh = h0 + sh, gwc = w0 + cb;
  const int cob = 16 * half;         // this block's c_out base

  const float* ybase = out + ((size_t)b * T + (t - 1)) * CHW;

  // stage channel-sum tile: sum of the two half-planes from step t-1
  for (int i = tid; i < 180; i += 256) {
    int rr = i / 18, cl = i % 18;
    int gh2 = h0 - 1 + rr, gw2 = w0 - 1 + cl;
    float v = 0.f;
    if ((unsigned)gh2 < (unsigned)H && (unsigned)gw2 < (unsigned)W) {
      const size_t ii = (size_t)b * HW + gh2 * W + gw2;
      v = s_in[ii] + s_in[BHW + ii];
    }
    sl[rr][cl] = v;
  }

  // l-plane read (channel-uniform)
  float4 l4 = *(const float4*)(lpl + (size_t)b * HW + (size_t)gh * W + gwc);
  float lnew[4] = {l4.x, l4.y, l4.z, l4.w};

  // y-prefetch slots (chunk-invariant addressing). 480 float4 per chunk.
  const int i0 = tid;
  const int cil0 = i0 / 60, rr0 = (i0 % 60) / 6, j0 = i0 % 6;
  const int gh0p = h0 - 1 + rr0, ws0p = w0 - 4 + 4 * j0;
  const bool ok0 = (unsigned)gh0p < (unsigned)H && (unsigned)ws0p <= (unsigned)(W - 4);
  const size_t yoff0 = (size_t)cil0 * HW + (size_t)(ok0 ? gh0p * W + ws0p : 0);
  float* const yd0 = &ysl[cil0][rr0][4 * j0];
  const int i1 = tid + 256;
  const bool use1 = i1 < 480;
  const int cil1 = (i1 / 60) & 7, rr1 = (i1 % 60) / 6, j1 = i1 % 6;
  const int gh1p = h0 - 1 + rr1, ws1p = w0 - 4 + 4 * j1;
  const bool ok1 = use1 && (unsigned)gh1p < (unsigned)H &&
                   (unsigned)ws1p <= (unsigned)(W - 4);
  const size_t yoff1 = (size_t)cil1 * HW + (size_t)(ok1 ? gh1p * W + ws1p : 0);
  float* const yd1 = &ysl[cil1][rr1][4 * j1];

  // weight prefetch: 288 float4 per chunk (this co-half, strided source)
  const float4* const wsrc = (const float4*)wtr;
  float4* const wlds = (float4*)&wsl[0][0][0];
  const int wsl0 = tid;                       // always < 288
  const int wc0 = wsl0 / 36, wk0 = (wsl0 % 36) / 4, wj0 = wsl0 & 3;
  const int wslot1 = tid + 256;
  const bool wuse1 = wslot1 < 288;            // tid < 32
  const int wc1 = (wslot1 / 36) & 7, wk1 = (wslot1 % 36) / 4, wj1 = wslot1 & 3;

  float4 y0v, y1v, w0v, w1v;
  auto prefetch = [&](int cc) {
    const float* yb = ybase + (size_t)cc * 8 * HW;
    y0v = ok0 ? *(const float4*)(yb + yoff0) : make_float4(0.f, 0.f, 0.f, 0.f);
    y1v = ok1 ? *(const float4*)(yb + yoff1) : make_float4(0.f, 0.f, 0.f, 0.f);
    w0v = wsrc[((cc * 8 + wc0) * 9 + wk0) * 8 + 4 * half + wj0];
    if (wuse1) w1v = wsrc[((cc * 8 + wc1) * 9 + wk1) * 8 + 4 * half + wj1];
  };
  prefetch(0);

  float acc[2][4] = {};

#pragma unroll 1
  for (int cc = 0; cc < 4; ++cc) {
    __syncthreads();  // previous chunk's LDS reads complete
    yd0[0] = y0v.x; yd0[1] = y0v.y; yd0[2] = y0v.z; yd0[3] = y0v.w;
    if (use1) { yd1[0] = y1v.x; yd1[1] = y1v.y; yd1[2] = y1v.z; yd1[3] = y1v.w; }
    wlds[wsl0] = w0v;
    if (wuse1) wlds[wslot1] = w1v;
    __syncthreads();  // LDS visible
    if (cc < 3) prefetch(cc + 1);  // next chunk's loads fly under these FMAs
    if (cc == 0) {
      float linc[4];
#pragma unroll
      for (int p = 0; p < 4; ++p) {
        const int c0 = cb + p;
        linc[p] = 0.5f * (sl[sh][c0] + sl[sh][c0 + 2] + sl[sh + 2][c0] +
                          sl[sh + 2][c0 + 2]) +
                  sl[sh][c0 + 1] + sl[sh + 2][c0 + 1] + sl[sh + 1][c0] +
                  sl[sh + 1][c0 + 2];
      }
#pragma unroll
      for (int p = 0; p < 4; ++p) lnew[p] = DL * lnew[p] + linc[p];
    }
#pragma unroll
    for (int cil = 0; cil < 8; ++cil) {
#pragma unroll
      for (int kh = 0; kh < 3; ++kh) {
        const float* rowp = &ysl[cil][sh + kh][0];
        float2 a2 = *(const float2*)(rowp + cb + 2);
        float4 m4 = *(const float4*)(rowp + cb + 4);
        float2 z2 = *(const float2*)(rowp + cb + 8);
        const float yrow[6] = {a2.y, m4.x, m4.y, m4.z, m4.w, z2.x};
#pragma unroll
        for (int kw = 0; kw < 3; ++kw) {
          float2 wk = *(const float2*)&wsl[cil][3 * kh + kw][2 * g];
          const float wq[2] = {wk.x, wk.y};
#pragma unroll
          for (int q = 0; q < 2; ++q)
#pragma unroll
            for (int p = 0; p < 4; ++p)
              acc[q][p] = fmaf(wq[q], yrow[p + kw], acc[q][p]);
        }
      }
    }
  }

  // epilogue: f/e update (e-fold), out write, chansum partials (this half)
  const float2 bc2 = *(const float2*)&bias[cob + 2 * g];
  const float bc[2] = {bc2.x, bc2.y};
  float sp[4] = {0.f, 0.f, 0.f, 0.f};
#pragma unroll
  for (int q = 0; q < 2; ++q) {
    const int c = cob + 2 * g + q;
    const size_t sidx = (size_t)b * CHW + (size_t)c * HW + (size_t)gh * W + gwc;
    const size_t oidx = (((size_t)b * T + t) * C + c) * (size_t)HW + (size_t)gh * W + gwc;
    float4 f4 = *(const float4*)(f + sidx);
    float4 e4 = *(const float4*)(e + sidx);
    float4 x4 = *(const float4*)(x + oidx);
    float fr[4] = {f4.x, f4.y, f4.z, f4.w};
    float er[4] = {e4.x, e4.y, e4.z, e4.w};
    float xr[4] = {x4.x, x4.y, x4.z, x4.w};
    float fo[4], eo[4], yn[4];
#pragma unroll
    for (int p = 0; p < 4; ++p) {
      float fn = DF * fr[p] + acc[q][p] + bc[q] + xr[p];
      float u = fmaf(0.5f * fn, lnew[p], fn);
      float yy = 1.f / (1.f + __expf(er[p] - u));
      fo[p] = fn;
      eo[p] = DE * er[p] + VE * yy;  // e_used(t+1)
      yn[p] = yy;
      sp[p] += yy;
    }
    *(float4*)(f + sidx) = make_float4(fo[0], fo[1], fo[2], fo[3]);
    *(float4*)(e + sidx) = make_float4(eo[0], eo[1], eo[2], eo[3]);
    *(float4*)(out + oidx) = make_float4(yn[0], yn[1], yn[2], yn[3]);
  }
  *(float4*)&sred[g][s][0] = make_float4(sp[0], sp[1], sp[2], sp[3]);
  __syncthreads();
  if (tid < 32) {  // g==0 threads span the tile
    float4 a = *(const float4*)&sred[0][tid][0];
#pragma unroll
    for (int gg = 1; gg < 8; ++gg) {
      float4 bq = *(const float4*)&sred[gg][tid][0];
      a.x += bq.x; a.y += bq.y; a.z += bq.z; a.w += bq.w;
    }
    const size_t pidx = (size_t)b * HW + (size_t)gh * W + gwc;
    *(float4*)(s_out + (size_t)half * BHW + pidx) = a;  // this half's plane
    if (half == 0)  // l channel-uniform: one writer (both halves compute same)
      *(float4*)(lpl + pidx) = make_float4(lnew[0], lnew[1], lnew[2], lnew[3]);
  }
}

}  // namespace

extern "C" void kernel_launch(void* const* d_in, const int* in_sizes, int n_in,
                              void* d_out, int out_size, void* d_ws, size_t ws_size,
                              hipStream_t stream) {
  (void)in_sizes; (void)n_in; (void)out_size; (void)ws_size;
  const float* x = (const float*)d_in[0];     // (B,T,C,H,W)
  const float* wgt = (const float*)d_in[1];   // (C,C,3,3)
  const float* bias = (const float*)d_in[2];  // (C,)
  float* out = (float*)d_out;                 // (B,T,C,H,W)

  float* ws = (float*)d_ws;
  float* f = ws;                    // NSTATE
  float* e = f + NSTATE;            // NSTATE
  float* lpl = e + NSTATE;          // BHW (l is channel-uniform)
  float* sA = lpl + BHW;            // 2*BHW (two co-half planes)
  float* sB = sA + 2 * BHW;         // 2*BHW
  float* wtr = sB + 2 * BHW;        // 9216

  k_wtr<<<36, 256, 0, stream>>>(wgt, wtr);
  k_step0<<<1024, 256, 0, stream>>>(x, bias, f, e, lpl, out, sA);

  float* s_in = sA;
  float* s_out = sB;
  for (int t = 1; t < T; ++t) {
    k_step<<<2048, 256, 0, stream>>>(x, wtr, bias, s_in, s_out, f, e, lpl, out, t);
    float* tmp = s_in; s_in = s_out; s_out = tmp;
  }
}